// Round 13
// baseline (89.479 us; speedup 1.0000x reference)
//
#include <hip/hip_runtime.h>
#include <stdint.h>
#include <math.h>

#define B_N 512
#define M_N 65536
#define D_N 256
#define C_N 10
#define TEMP_INV 14.285714285714286f   // 1/0.07
#define LOG2E_F 1.4426950408889634f
#define K2C (LOG2E_F * TEMP_INV)       // exp(x/T) = exp2(x*K2C)

typedef __attribute__((ext_vector_type(8))) __bf16 bf16x8;
typedef __attribute__((ext_vector_type(4))) float f32x4;

__device__ __forceinline__ unsigned short f2bf(float f) {
  unsigned int u = __float_as_uint(f);
  return (unsigned short)((u + 0x7FFFu + ((u >> 16) & 1u)) >> 16);  // RNE
}
__device__ __forceinline__ float bf2f(unsigned short s) {
  return __uint_as_float(((unsigned int)s) << 16);
}

// K1: fused normalize (verified R4-R8). Blocks [0,2048): pm -> bf16 pnb
// (row-major). Blocks [2048,2080): q -> qn f32 + qnb bf16 + qnbF
// ([kc][r][8] fragment layout). Block 0 inits accumulators.
__global__ __launch_bounds__(256) void k_norm(const float* __restrict__ pm,
                                              const float* __restrict__ q,
                                              unsigned short* __restrict__ pnb,
                                              float* __restrict__ qn,
                                              unsigned short* __restrict__ qnb,
                                              unsigned short* __restrict__ qnbF,
                                              float* __restrict__ P,
                                              int* __restrict__ cnt,
                                              float* __restrict__ Zt,
                                              float* __restrict__ Ss,
                                              float* __restrict__ ns_,
                                              float* __restrict__ out) {
  const int tid = threadIdx.x, w = tid >> 6, l = tid & 63;
  const int g = l >> 4, qs = l & 15;
  if (blockIdx.x == 0) {
    for (int i = tid; i < C_N * D_N; i += 256) P[i] = 0.f;
    if (tid < C_N) cnt[tid] = 0;
    for (int i = tid; i < B_N; i += 256) { Zt[i] = 0.f; Ss[i] = 0.f; ns_[i] = 0.f; }
    if (tid == 0) out[0] = 0.f;
  }
  if (blockIdx.x < 2048) {
    const int rbase = blockIdx.x * 32 + w * 8;
#pragma unroll
    for (int it = 0; it < 2; ++it) {
      const int r = rbase + it * 4 + g;
      const float* src = pm + (size_t)r * D_N;
      float4 v[4];
#pragma unroll
      for (int c = 0; c < 4; ++c) v[c] = *(const float4*)(src + qs * 4 + c * 64);
      float ss = 0.f;
#pragma unroll
      for (int c = 0; c < 4; ++c)
        ss += v[c].x * v[c].x + v[c].y * v[c].y + v[c].z * v[c].z + v[c].w * v[c].w;
      ss += __shfl_xor(ss, 1, 64);
      ss += __shfl_xor(ss, 2, 64);
      ss += __shfl_xor(ss, 4, 64);
      ss += __shfl_xor(ss, 8, 64);
      const float rv = 1.0f / fmaxf(sqrtf(ss), 1e-8f);
      unsigned short* dst = pnb + (size_t)r * D_N;
#pragma unroll
      for (int c = 0; c < 4; ++c) {
        ushort4 o;
        o.x = f2bf(v[c].x * rv); o.y = f2bf(v[c].y * rv);
        o.z = f2bf(v[c].z * rv); o.w = f2bf(v[c].w * rv);
        *(ushort4*)(dst + qs * 4 + c * 64) = o;
      }
    }
  } else {
    const int r = (blockIdx.x - 2048) * 16 + w * 4 + g;
    const float* src = q + (size_t)r * D_N;
    float4 v[4];
#pragma unroll
    for (int c = 0; c < 4; ++c) v[c] = *(const float4*)(src + qs * 4 + c * 64);
    float ss = 0.f;
#pragma unroll
    for (int c = 0; c < 4; ++c)
      ss += v[c].x * v[c].x + v[c].y * v[c].y + v[c].z * v[c].z + v[c].w * v[c].w;
    ss += __shfl_xor(ss, 1, 64);
    ss += __shfl_xor(ss, 2, 64);
    ss += __shfl_xor(ss, 4, 64);
    ss += __shfl_xor(ss, 8, 64);
    const float rv = 1.0f / fmaxf(sqrtf(ss), 1e-8f);
    float* dstf = qn + (size_t)r * D_N;
    unsigned short* dstb = qnb + (size_t)r * D_N;
#pragma unroll
    for (int c = 0; c < 4; ++c) {
      float4 o4;
      o4.x = v[c].x * rv; o4.y = v[c].y * rv; o4.z = v[c].z * rv; o4.w = v[c].w * rv;
      *(float4*)(dstf + qs * 4 + c * 64) = o4;
      ushort4 o;
      o.x = f2bf(o4.x); o.y = f2bf(o4.y); o.z = f2bf(o4.z); o.w = f2bf(o4.w);
      *(ushort4*)(dstb + qs * 4 + c * 64) = o;
      const int kc = (qs >> 1) + c * 8;          // 16B chunk index (0..31)
      *(ushort4*)(qnbF + (((size_t)kc * 512 + r) << 3) + (qs & 1) * 4) = o;
    }
  }
}

// K2: class partial sums (verified R5 design, standalone). 512 blocks x 256.
// One wave per row (ushort4/lane), wave-uniform switch into float4 register
// accumulators, cross-wave LDS merge, plain coalesced stores.
__global__ __launch_bounds__(256) void k_class(const unsigned short* __restrict__ pnb,
                                               const int* __restrict__ pl,
                                               float* __restrict__ part) {
  __shared__ float Pl[4 * C_N * D_N];                      // 40 KB
  const int tid = threadIdx.x, w = tid >> 6, lane = tid & 63;
  const int cb = blockIdx.x;
  const int rbase = cb * 128;
  float4 a0 = {0,0,0,0}, a1 = {0,0,0,0}, a2 = {0,0,0,0}, a3 = {0,0,0,0}, a4 = {0,0,0,0};
  float4 a5 = {0,0,0,0}, a6 = {0,0,0,0}, a7 = {0,0,0,0}, a8 = {0,0,0,0}, a9 = {0,0,0,0};
  for (int j = 0; j < 32; ++j) {
    const int row = rbase + j * 4 + w;                     // one row per wave
    const ushort4 u = *(const ushort4*)(pnb + (size_t)row * D_N + lane * 4);
    float4 v;
    v.x = bf2f(u.x); v.y = bf2f(u.y); v.z = bf2f(u.z); v.w = bf2f(u.w);
    const int cls = pl[row];                               // wave-uniform
    switch (cls) {
      case 0: a0.x += v.x; a0.y += v.y; a0.z += v.z; a0.w += v.w; break;
      case 1: a1.x += v.x; a1.y += v.y; a1.z += v.z; a1.w += v.w; break;
      case 2: a2.x += v.x; a2.y += v.y; a2.z += v.z; a2.w += v.w; break;
      case 3: a3.x += v.x; a3.y += v.y; a3.z += v.z; a3.w += v.w; break;
      case 4: a4.x += v.x; a4.y += v.y; a4.z += v.z; a4.w += v.w; break;
      case 5: a5.x += v.x; a5.y += v.y; a5.z += v.z; a5.w += v.w; break;
      case 6: a6.x += v.x; a6.y += v.y; a6.z += v.z; a6.w += v.w; break;
      case 7: a7.x += v.x; a7.y += v.y; a7.z += v.z; a7.w += v.w; break;
      case 8: a8.x += v.x; a8.y += v.y; a8.z += v.z; a8.w += v.w; break;
      default: a9.x += v.x; a9.y += v.y; a9.z += v.z; a9.w += v.w; break;
    }
  }
#define WRCLS(k, ak) *(float4*)(Pl + ((w * 10 + (k)) * 256 + lane * 4)) = ak;
  WRCLS(0, a0) WRCLS(1, a1) WRCLS(2, a2) WRCLS(3, a3) WRCLS(4, a4)
  WRCLS(5, a5) WRCLS(6, a6) WRCLS(7, a7) WRCLS(8, a8) WRCLS(9, a9)
#undef WRCLS
  __syncthreads();
  float* dst = part + (size_t)cb * (C_N * D_N);
  for (int i = tid; i < C_N * D_N; i += 256)
    dst[i] = Pl[i] + Pl[2560 + i] + Pl[5120 + i] + Pl[7680 + i];
}

// K3: GEMM kernel (512 threads = 8 waves).
//   blocks [0,1024): Z_mem GEMM: 64-row B-tile reg-staged -> 544B-pitch LDS
//     (verified R6 pattern, conflict-free), ONE barrier. A-slice batch-loaded
//     into const-indexed af[16] + sched_barrier(0) pin -> one latency exposure
//     per 64-MFMA pass. Z -> Zpart[mt][512], no atomics.
//   blocks [1024,1040): src branch (verified).
__global__ __launch_bounds__(512, 2) void k_gemm(const unsigned short* __restrict__ pnb,
                                                 const unsigned short* __restrict__ qnb,
                                                 const unsigned short* __restrict__ qnbF,
                                                 const int* __restrict__ labels,
                                                 float* __restrict__ Zt,
                                                 float* __restrict__ Ss,
                                                 float* __restrict__ ns_,
                                                 float* __restrict__ Zpart) {
  __shared__ __align__(16) unsigned char smem[36864];
  const int bid = blockIdx.x;
  const int tid = threadIdx.x, w = tid >> 6, lane = tid & 63;
  const int rsel = lane & 15, hi = lane >> 4;

  if (bid < 1024) {
    // ---------------- Z_mem GEMM ----------------
    const int mt = bid;
    unsigned short* Bs = (unsigned short*)smem;            // 64 rows x 544B = 34816
    float* zall = (float*)(smem + 34816);                  // [512]
    const unsigned short* Bb = pnb + (size_t)mt * 64 * D_N;
    zall[tid] = 0.f;
    // reg-stage B tile: 64 rows x 256 k -> 544B pitch (R6-verified).
    {
      bf16x8 t8[4];
#pragma unroll
      for (int i = 0; i < 4; ++i) {
        const int c = i * 512 + tid;
        t8[i] = *(const bf16x8*)(Bb + (size_t)c * 8);      // linear, coalesced
      }
#pragma unroll
      for (int i = 0; i < 4; ++i) {
        const int c = i * 512 + tid;
        const int r = c >> 5, s = c & 31;
        *(bf16x8*)((char*)Bs + r * 544 + s * 16) = t8[i];  // padded pitch
      }
    }
    __syncthreads();   // the ONLY barrier before the flush

#pragma unroll 1
    for (int pass = 0; pass < 2; ++pass) {
      const int qbase = pass * 256 + w * 32;
      // batch-load the wave's ENTIRE A-slice (32q x K256): 16 independent
      // loads into a const-indexed array, PINNED by sched_barrier(0).
      bf16x8 af[16];
#pragma unroll
      for (int t = 0; t < 16; ++t)
        af[t] = *(const bf16x8*)(qnbF +
            (((size_t)((t & 7) * 4 + hi) * 512 + qbase + (t >> 3) * 16 + rsel) << 3));
      __builtin_amdgcn_sched_barrier(0);   // pin loads above the MFMA loop

      f32x4 acc[2][4];
#pragma unroll
      for (int ni = 0; ni < 4; ++ni) {
        acc[0][ni] = (f32x4){0.f, 0.f, 0.f, 0.f};
        acc[1][ni] = (f32x4){0.f, 0.f, 0.f, 0.f};
      }
#pragma unroll
      for (int it = 0; it < 8; ++it) {
        const int kc = it * 4 + hi;
#pragma unroll
        for (int ni = 0; ni < 4; ++ni) {
          const bf16x8 b = *(const bf16x8*)((const char*)Bs + (ni * 16 + rsel) * 544 + kc * 16);
          acc[0][ni] = __builtin_amdgcn_mfma_f32_16x16x32_bf16(af[it], b, acc[0][ni], 0, 0, 0);
          acc[1][ni] = __builtin_amdgcn_mfma_f32_16x16x32_bf16(af[8 + it], b, acc[1][ni], 0, 0, 0);
        }
      }
      // epilogue: sum exp over this block's 64 m-cols
#pragma unroll
      for (int mi = 0; mi < 2; ++mi) {
        float sv[4] = {0.f, 0.f, 0.f, 0.f};
#pragma unroll
        for (int ni = 0; ni < 4; ++ni)
#pragma unroll
          for (int rg = 0; rg < 4; ++rg)
            sv[rg] += __builtin_amdgcn_exp2f(acc[mi][ni][rg] * K2C);
#pragma unroll
        for (int rg = 0; rg < 4; ++rg) {
          float v = sv[rg];
          v += __shfl_xor(v, 1, 64);
          v += __shfl_xor(v, 2, 64);
          v += __shfl_xor(v, 4, 64);
          v += __shfl_xor(v, 8, 64);
          if (rsel == 0)
            zall[qbase + mi * 16 + hi * 4 + rg] = v;       // owner-unique
        }
      }
    }
    __syncthreads();
    Zpart[(size_t)mt * 512 + tid] = zall[tid];             // coalesced, no atomics
  } else {
    // ---------------- src branch (verified, 8-wave) ----------------
    unsigned short* As = (unsigned short*)smem;            // 128x64
    unsigned short* Bs2 = (unsigned short*)(smem + 16384); // 128x64
    int* labR = (int*)(smem + 32768);
    int* labJ = (int*)(smem + 33280);
    float* zr = (float*)(smem + 33792);
    float* sr = (float*)(smem + 34304);
    float* nr = (float*)(smem + 34816);
    const int sb_id = bid - 1024;
    const int bt2 = sb_id >> 2, jt = sb_id & 3;
    const unsigned short* Ab = qnb + (size_t)(bt2 * 128) * D_N;
    const unsigned short* Bb = qnb + (size_t)(jt * 128) * D_N;
    if (tid < 128) {
      labR[tid] = labels[bt2 * 128 + tid];
      labJ[tid] = labels[jt * 128 + tid];
      zr[tid] = 0.f; sr[tid] = 0.f; nr[tid] = 0.f;
    }
    f32x4 acc[4][2];
#pragma unroll
    for (int mi = 0; mi < 4; ++mi)
#pragma unroll
      for (int ni = 0; ni < 2; ++ni)
        acc[mi][ni] = (f32x4){0.f, 0.f, 0.f, 0.f};
    const int wr = w >> 2, wc = w & 3;                     // 2 x 4 wave grid
#pragma unroll 1
    for (int ks = 0; ks < 4; ++ks) {
      const int kk = ks * 64;
#pragma unroll
      for (int i = 0; i < 2; ++i) {
        const int cbase = i * 512 + w * 64;
        const int c = cbase + lane;
        const int r = c >> 3;
        const int ss2 = (c & 7) ^ (r & 7);
        __builtin_amdgcn_global_load_lds(
            (const __attribute__((address_space(1))) void*)(Ab + (size_t)r * D_N + kk + ss2 * 8),
            (__attribute__((address_space(3))) void*)(As + cbase * 8), 16, 0, 0);
        __builtin_amdgcn_global_load_lds(
            (const __attribute__((address_space(1))) void*)(Bb + (size_t)r * D_N + kk + ss2 * 8),
            (__attribute__((address_space(3))) void*)(Bs2 + cbase * 8), 16, 0, 0);
      }
      __syncthreads();
#pragma unroll 1
      for (int ksl = 0; ksl < 2; ++ksl) {
        const int sb = ksl * 4 + hi;
        bf16x8 af[4], bfr[2];
#pragma unroll
        for (int mi = 0; mi < 4; ++mi) {
          const int r = wr * 64 + mi * 16 + rsel;
          af[mi] = *(const bf16x8*)((const char*)As + r * 128 + ((sb ^ (r & 7)) * 16));
        }
#pragma unroll
        for (int ni = 0; ni < 2; ++ni) {
          const int r = wc * 32 + ni * 16 + rsel;
          bfr[ni] = *(const bf16x8*)((const char*)Bs2 + r * 128 + ((sb ^ (r & 7)) * 16));
        }
#pragma unroll
        for (int mi = 0; mi < 4; ++mi)
#pragma unroll
          for (int ni = 0; ni < 2; ++ni)
            acc[mi][ni] = __builtin_amdgcn_mfma_f32_16x16x32_bf16(af[mi], bfr[ni], acc[mi][ni], 0, 0, 0);
      }
      __syncthreads();
    }
#pragma unroll
    for (int mi = 0; mi < 4; ++mi) {
      float zs[4] = {0.f, 0.f, 0.f, 0.f};
      float sv[4] = {0.f, 0.f, 0.f, 0.f};
      float nv[4] = {0.f, 0.f, 0.f, 0.f};
#pragma unroll
      for (int ni = 0; ni < 2; ++ni) {
        const int j_loc = wc * 32 + ni * 16 + rsel;
        const int jg = jt * 128 + j_loc;
        const int lj = labJ[j_loc];
#pragma unroll
        for (int rg_ = 0; rg_ < 4; ++rg_) {
          const int r_loc = wr * 64 + mi * 16 + hi * 4 + rg_;
          const int rg = bt2 * 128 + r_loc;
          const float lg = acc[mi][ni][rg_] * TEMP_INV - TEMP_INV;
          if (rg != jg) {
            zs[rg_] += __builtin_amdgcn_exp2f(lg * LOG2E_F);
            if (labR[r_loc] == lj) { sv[rg_] += lg; nv[rg_] += 1.f; }
          }
        }
      }
#pragma unroll
      for (int rg_ = 0; rg_ < 4; ++rg_) {
        float z = zs[rg_], s = sv[rg_], n = nv[rg_];
        z += __shfl_xor(z, 1, 64); z += __shfl_xor(z, 2, 64);
        z += __shfl_xor(z, 4, 64); z += __shfl_xor(z, 8, 64);
        s += __shfl_xor(s, 1, 64); s += __shfl_xor(s, 2, 64);
        s += __shfl_xor(s, 4, 64); s += __shfl_xor(s, 8, 64);
        n += __shfl_xor(n, 1, 64); n += __shfl_xor(n, 2, 64);
        n += __shfl_xor(n, 4, 64); n += __shfl_xor(n, 8, 64);
        if (rsel == 0) {
          const int r_loc = wr * 64 + mi * 16 + hi * 4 + rg_;
          atomicAdd(&zr[r_loc], z);
          atomicAdd(&sr[r_loc], s);
          atomicAdd(&nr[r_loc], n);
        }
      }
    }
    __syncthreads();
    if (tid < 128) {
      atomicAdd(&Zt[bt2 * 128 + tid], zr[tid]);
      atomicAdd(&Ss[bt2 * 128 + tid], sr[tid]);
      atomicAdd(&ns_[bt2 * 128 + tid], nr[tid]);
    }
  }
}

// K4: fused reductions. Blocks [0,40): class partials (512 rows) -> P, counts.
// Blocks [40,48): Zpart columns (1024 rows) -> Zt (+=).
__global__ __launch_bounds__(256) void k_reduce2(const float* __restrict__ part,
                                                 const int* __restrict__ pl,
                                                 const float* __restrict__ Zpart,
                                                 float* __restrict__ P,
                                                 int* __restrict__ cnt,
                                                 float* __restrict__ Zt) {
  const int tid = threadIdx.x, w = tid >> 6, lane = tid & 63;
  if (blockIdx.x < 40) {
    __shared__ int xs[4];
    const int c = blockIdx.x >> 2, q = blockIdx.x & 3;
    float s = 0.f;
#pragma unroll 8
    for (int i = 0; i < 128; ++i)
      s += part[(size_t)(q * 128 + i) * (C_N * D_N) + c * 256 + tid];
    atomicAdd(&P[c * 256 + tid], s);
    int x = 0;
    const int* plq = pl + q * 16384;
#pragma unroll 8
    for (int jj = 0; jj < 64; ++jj)
      x += (plq[jj * 256 + tid] == c) ? 1 : 0;
    x += __shfl_xor(x, 32, 64);
    x += __shfl_xor(x, 16, 64);
    x += __shfl_xor(x, 8, 64);
    x += __shfl_xor(x, 4, 64);
    x += __shfl_xor(x, 2, 64);
    x += __shfl_xor(x, 1, 64);
    if (lane == 0) xs[w] = x;
    __syncthreads();
    if (tid == 0) atomicAdd(&cnt[c], xs[0] + xs[1] + xs[2] + xs[3]);
  } else {
    __shared__ float zl[4][64];
    const int zb = blockIdx.x - 40;
    const int b = zb * 64 + (tid & 63);
    const int s = tid >> 6;
    float acc = 0.f;
#pragma unroll 8
    for (int k = 0; k < 256; ++k)
      acc += Zpart[(size_t)(s * 256 + k) * 512 + b];
    zl[s][tid & 63] = acc;
    __syncthreads();
    if (tid < 64)
      Zt[zb * 64 + tid] += zl[0][tid] + zl[1][tid] + zl[2][tid] + zl[3][tid];
  }
}

// K5: loss. 128 blocks, 1 row per wave.
__global__ __launch_bounds__(256) void k_final(const float* __restrict__ qn,
                                               const int* __restrict__ labels,
                                               const float* __restrict__ P,
                                               const int* __restrict__ cnt,
                                               const float* __restrict__ Zt,
                                               const float* __restrict__ Ss,
                                               const float* __restrict__ ns_,
                                               float* __restrict__ out) {
  __shared__ float partl[4];
  const int tid = threadIdx.x, w = tid >> 6, lane = tid & 63;
  const int b = blockIdx.x * 4 + w;
  const int cls = labels[b];
  const float4 v = *(const float4*)(qn + (size_t)b * D_N + lane * 4);
  const float4 p = *(const float4*)(P + (size_t)cls * D_N + lane * 4);
  float d = v.x * p.x + v.y * p.y + v.z * p.z + v.w * p.w;
  d += __shfl_xor(d, 32, 64);
  d += __shfl_xor(d, 16, 64);
  d += __shfl_xor(d, 8, 64);
  d += __shfl_xor(d, 4, 64);
  d += __shfl_xor(d, 2, 64);
  d += __shfl_xor(d, 1, 64);
  if (lane == 0) {
    const float smem_ = d * TEMP_INV;
    const float ntot = ns_[b] + (float)cnt[cls];
    partl[w] = (Ss[b] + smem_) / ntot - logf(Zt[b]);
  }
  __syncthreads();
  if (tid == 0)
    atomicAdd(out, -(partl[0] + partl[1] + partl[2] + partl[3]) * (1.0f / (float)B_N));
}

extern "C" void kernel_launch(void* const* d_in, const int* in_sizes, int n_in,
                              void* d_out, int out_size, void* d_ws, size_t ws_size,
                              hipStream_t stream) {
  const float* q = (const float*)d_in[0];
  const int* labels = (const int*)d_in[1];
  const float* pm = (const float*)d_in[2];
  const int* pl = (const int*)d_in[3];
  float* out = (float*)d_out;

  char* wsb = (char*)d_ws;
  unsigned short* pnb = (unsigned short*)wsb;              // 33,554,432 B
  float* qn = (float*)(wsb + 33554432);                    // 524,288 B
  unsigned short* qnb = (unsigned short*)(wsb + 34078720); // 262,144 B
  unsigned short* qnbF = (unsigned short*)(wsb + 34340864);// 262,144 B
  float* P = (float*)(wsb + 34603008);                     // 10,240 B
  int* cnt = (int*)(wsb + 34613248);                       // 64 B
  float* Zt = (float*)(wsb + 34613312);                    // 2,048 B
  float* Ss = (float*)(wsb + 34615360);                    // 2,048 B
  float* ns_ = (float*)(wsb + 34617408);                   // 2,048 B
  float* part = (float*)(wsb + 34619456);                  // 512*2560*4 = 5,242,880 B
  float* Zpart = (float*)(wsb + 39862336);                 // 1024*512*4 = 2,097,152 B

  k_norm<<<2080, 256, 0, stream>>>(pm, q, pnb, qn, qnb, qnbF, P, cnt, Zt, Ss, ns_, out);
  k_class<<<512, 256, 0, stream>>>(pnb, pl, part);
  k_gemm<<<1040, 512, 0, stream>>>(pnb, qnb, qnbF, labels, Zt, Ss, ns_, Zpart);
  k_reduce2<<<48, 256, 0, stream>>>(part, pl, Zpart, P, cnt, Zt);
  k_final<<<128, 256, 0, stream>>>(qn, labels, P, cnt, Zt, Ss, ns_, out);
}